// Round 4
// baseline (750.604 us; speedup 1.0000x reference)
//
#include <hip/hip_runtime.h>

#define NN 100000
#define NE 1600000
#define NBUCK 782  // ceil(NN/128), bucket = dst >> 7

struct alignas(8) US4 { unsigned short x, y, z, w; };

__device__ __forceinline__ float bfu(unsigned int hw) { return __uint_as_float(hw << 16); }
__device__ __forceinline__ unsigned short f2bf(float f) {
    unsigned int u = __float_as_uint(f);
    return (unsigned short)((u + 0x7fffu + ((u >> 16) & 1u)) >> 16);
}

// ---------------- CSR build (bucketed, 2 passes) ----------------

__global__ __launch_bounds__(256) void k_hist(const int* __restrict__ dst,
                                              int* __restrict__ bucket_cnt) {
    __shared__ int hist[NBUCK];
    int tid = threadIdx.x;
    for (int i = tid; i < NBUCK; i += 256) hist[i] = 0;
    __syncthreads();
    int stride = gridDim.x * 256;
    for (int e = blockIdx.x * 256 + tid; e < NE; e += stride)
        atomicAdd(&hist[dst[e] >> 7], 1);
    __syncthreads();
    for (int i = tid; i < NBUCK; i += 256)
        if (hist[i]) atomicAdd(&bucket_cnt[i], hist[i]);
}

__global__ __launch_bounds__(1024) void k_bscan(const int* __restrict__ bucket_cnt,
                                                int* __restrict__ bucket_base,
                                                int* __restrict__ bucket_cursor) {
    __shared__ int tmp[1024];
    int t = threadIdx.x;
    int v = (t < NBUCK) ? bucket_cnt[t] : 0;
    tmp[t] = v;
    __syncthreads();
    for (int off = 1; off < 1024; off <<= 1) {
        int u = (t >= off) ? tmp[t - off] : 0;
        __syncthreads();
        tmp[t] += u;
        __syncthreads();
    }
    int excl = tmp[t] - v;
    if (t < NBUCK) {
        bucket_base[t] = excl;
        bucket_cursor[t] = excl;
    }
    if (t == 0) bucket_base[NBUCK] = NE;
}

// scatter (src,dst) pairs into bucket-ordered E2; fold in out-degree histogram
__global__ __launch_bounds__(256) void k_pairs(const int* __restrict__ src,
                                               const int* __restrict__ dst,
                                               int* __restrict__ bucket_cursor,
                                               int* __restrict__ cnt_out,
                                               int2* __restrict__ E2) {
    int e = blockIdx.x * 256 + threadIdx.x;
    if (e >= NE) return;
    int s = src[e], d = dst[e];
    atomicAdd(&cnt_out[s], 1);
    int pos = atomicAdd(&bucket_cursor[d >> 7], 1);
    E2[pos] = make_int2(s, d);
}

// per-bucket: LDS count+scan+cursor -> row_start, r_in, r_out, csr (L2-window writes)
__global__ __launch_bounds__(256) void k_bcsr(const int2* __restrict__ E2,
                                              const int* __restrict__ bucket_base,
                                              const int* __restrict__ cnt_out,
                                              int* __restrict__ row_start,
                                              float* __restrict__ r_in,
                                              float* __restrict__ r_out,
                                              int* __restrict__ csr) {
    __shared__ int cnt[128], cur[128];
    int tid = threadIdx.x;
    int b = blockIdx.x;
    int base = bucket_base[b], end = bucket_base[b + 1];
    if (tid < 128) cnt[tid] = 0;
    __syncthreads();
    for (int i = base + tid; i < end; i += 256) atomicAdd(&cnt[E2[i].y & 127], 1);
    __syncthreads();
    int v = (tid < 128) ? cnt[tid] : 0;
    for (int off = 1; off < 128; off <<= 1) {
        int u = (tid >= off && tid < 128) ? cnt[tid - off] : 0;
        __syncthreads();
        if (tid < 128) cnt[tid] += u;
        __syncthreads();
    }
    if (tid < 128) {
        int excl = cnt[tid] - v;  // exclusive scan within bucket
        cur[tid] = excl;
        int node = b * 128 + tid;
        if (node <= NN) row_start[node] = base + excl;
        if (node < NN) {
            r_in[node] = rsqrtf((float)max(v, 1));
            r_out[node] = rsqrtf((float)max(cnt_out[node], 1));
        }
    }
    __syncthreads();
    for (int i = base + tid; i < end; i += 256) {
        int2 e = E2[i];
        int pos = atomicAdd(&cur[e.y & 127], 1);
        csr[base + pos] = e.x;
    }
}

// ---------------- dense GEMMs ----------------

// A(bf16) = (x @ W0) * r_out.  64 nodes/block, thread = 4m x 4n, K=128 in two halves.
__global__ __launch_bounds__(256) void k_gemm0(const float* __restrict__ x,
                                               const float* __restrict__ W0,
                                               const float* __restrict__ r_out,
                                               unsigned short* __restrict__ A) {
    __shared__ float xl[64 * 129];
    __shared__ float wl[64 * 64];
    int tid = threadIdx.x;
    int m0 = blockIdx.x * 64;
#pragma unroll
    for (int i = 0; i < 8; ++i) {
        int idx = i * 256 + tid;
        int m = idx >> 5, kc = idx & 31;
        int gm = min(m0 + m, NN - 1);
        float4 v = *(const float4*)&x[(size_t)gm * 128 + kc * 4];
        float* p = &xl[m * 129 + kc * 4];
        p[0] = v.x; p[1] = v.y; p[2] = v.z; p[3] = v.w;
    }
    int tn = tid & 15, tm = tid >> 4;
    float acc[4][4] = {};
    const float4* W4 = (const float4*)W0;
    float4* wl4 = (float4*)wl;
    for (int h = 0; h < 2; ++h) {
        __syncthreads();
#pragma unroll
        for (int i = 0; i < 4; ++i) wl4[i * 256 + tid] = W4[h * 1024 + i * 256 + tid];
        __syncthreads();
#pragma unroll 4
        for (int k = 0; k < 64; ++k) {
            int kk = h * 64 + k;
            float4 wv = *(const float4*)&wl[k * 64 + tn * 4];
            float xv[4];
#pragma unroll
            for (int i = 0; i < 4; ++i) xv[i] = xl[(tm * 4 + i) * 129 + kk];
#pragma unroll
            for (int i = 0; i < 4; ++i) {
                acc[i][0] = fmaf(xv[i], wv.x, acc[i][0]);
                acc[i][1] = fmaf(xv[i], wv.y, acc[i][1]);
                acc[i][2] = fmaf(xv[i], wv.z, acc[i][2]);
                acc[i][3] = fmaf(xv[i], wv.w, acc[i][3]);
            }
        }
    }
#pragma unroll
    for (int i = 0; i < 4; ++i) {
        int m = m0 + tm * 4 + i;
        if (m < NN) {
            float ro = r_out[m];
            US4 o = {f2bf(acc[i][0] * ro), f2bf(acc[i][1] * ro),
                     f2bf(acc[i][2] * ro), f2bf(acc[i][3] * ro)};
            *(US4*)&A[(size_t)m * 64 + tn * 4] = o;
        }
    }
}

// C = (relu(G @ W1 + b1) @ W2) * r_out.  64 nodes/block.
__global__ __launch_bounds__(256) void k_mlp(const float* __restrict__ G,
                                             const float* __restrict__ W1,
                                             const float* __restrict__ b1,
                                             const float* __restrict__ W2,
                                             const float* __restrict__ r_out,
                                             float* __restrict__ C) {
    __shared__ float gl[64 * 65];
    __shared__ float w1l[64 * 64];
    __shared__ float w2l[64 * 16];
    int tid = threadIdx.x;
    int m0 = blockIdx.x * 64;
#pragma unroll
    for (int i = 0; i < 4; ++i) {
        int idx = i * 256 + tid;
        int m = idx >> 4, kc = idx & 15;
        int gm = min(m0 + m, NN - 1);
        float4 v = *(const float4*)&G[(size_t)gm * 64 + kc * 4];
        float* p = &gl[m * 65 + kc * 4];
        p[0] = v.x; p[1] = v.y; p[2] = v.z; p[3] = v.w;
    }
    float4* w1l4 = (float4*)w1l;
    const float4* W1_4 = (const float4*)W1;
#pragma unroll
    for (int i = 0; i < 4; ++i) w1l4[i * 256 + tid] = W1_4[i * 256 + tid];
    ((float4*)w2l)[tid] = ((const float4*)W2)[tid];
    __syncthreads();
    int tn = tid & 15, tm = tid >> 4;
    float acc[4][4] = {};
#pragma unroll 4
    for (int k = 0; k < 64; ++k) {
        float4 wv = *(const float4*)&w1l[k * 64 + tn * 4];
        float xv[4];
#pragma unroll
        for (int i = 0; i < 4; ++i) xv[i] = gl[(tm * 4 + i) * 65 + k];
#pragma unroll
        for (int i = 0; i < 4; ++i) {
            acc[i][0] = fmaf(xv[i], wv.x, acc[i][0]);
            acc[i][1] = fmaf(xv[i], wv.y, acc[i][1]);
            acc[i][2] = fmaf(xv[i], wv.z, acc[i][2]);
            acc[i][3] = fmaf(xv[i], wv.w, acc[i][3]);
        }
    }
    float4 bb = *(const float4*)&b1[tn * 4];
    __syncthreads();
#pragma unroll
    for (int i = 0; i < 4; ++i) {
        gl[(tm * 4 + i) * 65 + tn * 4 + 0] = fmaxf(acc[i][0] + bb.x, 0.f);
        gl[(tm * 4 + i) * 65 + tn * 4 + 1] = fmaxf(acc[i][1] + bb.y, 0.f);
        gl[(tm * 4 + i) * 65 + tn * 4 + 2] = fmaxf(acc[i][2] + bb.z, 0.f);
        gl[(tm * 4 + i) * 65 + tn * 4 + 3] = fmaxf(acc[i][3] + bb.w, 0.f);
    }
    __syncthreads();
    int m = tid >> 2, n0 = (tid & 3) * 4;
    float a2[4] = {};
#pragma unroll 8
    for (int k = 0; k < 64; ++k) {
        float zv = gl[m * 65 + k];
        float4 wv = *(const float4*)&w2l[k * 16 + n0];
        a2[0] = fmaf(zv, wv.x, a2[0]);
        a2[1] = fmaf(zv, wv.y, a2[1]);
        a2[2] = fmaf(zv, wv.z, a2[2]);
        a2[3] = fmaf(zv, wv.w, a2[3]);
    }
    int node = m0 + m;
    if (node < NN) {
        float ro = r_out[node];
        float4 o = {a2[0] * ro, a2[1] * ro, a2[2] * ro, a2[3] * ro};
        *(float4*)&C[(size_t)node * 16 + n0] = o;
    }
}

// ---------------- gathers ----------------

// d=64 bf16 gather, 1 node/wave, 8 edges in flight (16 lanes x 8B each).
// MODE 0: o16 = bf16(relu(agg*r_in + bias)*r_out)
// MODE 1: o32 = agg*r_in  (fp32, feeds k_mlp)
template <int MODE>
__global__ __launch_bounds__(256) void k_gather64(const int* __restrict__ row_start,
                                                  const int* __restrict__ csr,
                                                  const unsigned short* __restrict__ h,
                                                  const float* __restrict__ r_in,
                                                  const float* __restrict__ r_out,
                                                  const float* __restrict__ bias,
                                                  unsigned short* __restrict__ o16,
                                                  float* __restrict__ o32) {
    int tid = threadIdx.x;
    int wave = tid >> 6, lane = tid & 63;
    int n = blockIdx.x * 4 + wave;
    int jb = row_start[n], je = row_start[n + 1];
    int g = lane >> 4, f = lane & 15;
    float4 a0 = {0, 0, 0, 0}, a1 = {0, 0, 0, 0};
    for (int j = jb; j < je; j += 8) {
        int i0 = j + g, i1 = i0 + 4;
        int s0 = csr[min(i0, je - 1)];
        int s1 = csr[min(i1, je - 1)];
        uint2 u0 = *(const uint2*)(h + (size_t)s0 * 64 + f * 4);
        uint2 u1 = *(const uint2*)(h + (size_t)s1 * 64 + f * 4);
        float w0 = (i0 < je) ? 1.f : 0.f;
        float w1 = (i1 < je) ? 1.f : 0.f;
        a0.x = fmaf(w0, bfu(u0.x & 0xffffu), a0.x);
        a0.y = fmaf(w0, bfu(u0.x >> 16), a0.y);
        a0.z = fmaf(w0, bfu(u0.y & 0xffffu), a0.z);
        a0.w = fmaf(w0, bfu(u0.y >> 16), a0.w);
        a1.x = fmaf(w1, bfu(u1.x & 0xffffu), a1.x);
        a1.y = fmaf(w1, bfu(u1.x >> 16), a1.y);
        a1.z = fmaf(w1, bfu(u1.y & 0xffffu), a1.z);
        a1.w = fmaf(w1, bfu(u1.y >> 16), a1.w);
    }
    a0.x += a1.x; a0.y += a1.y; a0.z += a1.z; a0.w += a1.w;
    a0.x += __shfl_xor(a0.x, 16); a0.y += __shfl_xor(a0.y, 16);
    a0.z += __shfl_xor(a0.z, 16); a0.w += __shfl_xor(a0.w, 16);
    a0.x += __shfl_xor(a0.x, 32); a0.y += __shfl_xor(a0.y, 32);
    a0.z += __shfl_xor(a0.z, 32); a0.w += __shfl_xor(a0.w, 32);
    if (g == 0) {
        float ri = r_in[n];
        if (MODE == 0) {
            float ro = r_out[n];
            float4 bb = *(const float4*)&bias[f * 4];
            US4 o = {f2bf(fmaxf(fmaf(a0.x, ri, bb.x), 0.f) * ro),
                     f2bf(fmaxf(fmaf(a0.y, ri, bb.y), 0.f) * ro),
                     f2bf(fmaxf(fmaf(a0.z, ri, bb.z), 0.f) * ro),
                     f2bf(fmaxf(fmaf(a0.w, ri, bb.w), 0.f) * ro)};
            *(US4*)&o16[(size_t)n * 64 + f * 4] = o;
        } else {
            float4 o = {a0.x * ri, a0.y * ri, a0.z * ri, a0.w * ri};
            *(float4*)&o32[(size_t)n * 64 + f * 4] = o;
        }
    }
}

// d=16 fp32 gather: out = agg*r_in + b2
__global__ __launch_bounds__(256) void k_gather16(const int* __restrict__ row_start,
                                                  const int* __restrict__ csr,
                                                  const float* __restrict__ C,
                                                  const float* __restrict__ r_in,
                                                  const float* __restrict__ b2,
                                                  float* __restrict__ out) {
    int tid = threadIdx.x;
    int wave = tid >> 6, lane = tid & 63;
    int n = blockIdx.x * 4 + wave;
    int jb = row_start[n], je = row_start[n + 1];
    int g = lane >> 2, f = lane & 3;
    float4 acc = {0, 0, 0, 0};
    for (int j = jb; j < je; j += 16) {
        int i0 = j + g;
        int s = csr[min(i0, je - 1)];
        float4 v = *(const float4*)&C[(size_t)s * 16 + f * 4];
        float w = (i0 < je) ? 1.f : 0.f;
        acc.x = fmaf(w, v.x, acc.x); acc.y = fmaf(w, v.y, acc.y);
        acc.z = fmaf(w, v.z, acc.z); acc.w = fmaf(w, v.w, acc.w);
    }
#pragma unroll
    for (int m = 4; m <= 32; m <<= 1) {
        acc.x += __shfl_xor(acc.x, m); acc.y += __shfl_xor(acc.y, m);
        acc.z += __shfl_xor(acc.z, m); acc.w += __shfl_xor(acc.w, m);
    }
    if (g == 0) {
        float ri = r_in[n];
        float4 bb = *(const float4*)&b2[f * 4];
        float4 o;
        o.x = fmaf(acc.x, ri, bb.x); o.y = fmaf(acc.y, ri, bb.y);
        o.z = fmaf(acc.z, ri, bb.z); o.w = fmaf(acc.w, ri, bb.w);
        *(float4*)&out[(size_t)n * 16 + f * 4] = o;
    }
}

extern "C" void kernel_launch(void* const* d_in, const int* in_sizes, int n_in,
                              void* d_out, int out_size, void* d_ws, size_t ws_size,
                              hipStream_t stream) {
    const float* feats = (const float*)d_in[0];
    const int* src = (const int*)d_in[1];
    const int* dst = (const int*)d_in[2];
    const float* W0 = (const float*)d_in[3];
    const float* b0 = (const float*)d_in[4];
    const float* W1 = (const float*)d_in[5];
    const float* b1 = (const float*)d_in[6];
    const float* W2 = (const float*)d_in[7];
    const float* b2 = (const float*)d_in[8];
    float* out = (float*)d_out;

    // ws (floats): r_out[NN] | r_in[NN] | row_start[NN+16] | csr[NE] |
    //   R1[64NN]  (E2[NE int2] -> A[64NN bf16] -> G[64NN f32], sequential lifetimes)
    //   B[32NN]   (64NN bf16)
    //   C[16NN]   (f32; transients cnt_out/bucket_* alias it early)
    float* ws = (float*)d_ws;
    float* r_out = ws;
    float* r_in = ws + NN;
    int* row_start = (int*)(ws + 2 * NN);
    int* csr = (int*)(ws + 3 * NN + 16);
    float* R1 = ws + 3 * NN + 16 + NE;
    int2* E2 = (int2*)R1;
    unsigned short* A = (unsigned short*)R1;
    float* G = R1;
    unsigned short* B = (unsigned short*)(R1 + (size_t)64 * NN);
    float* C = R1 + (size_t)64 * NN + (size_t)32 * NN;
    int* cnt_out = (int*)C;
    int* bucket_cnt = cnt_out + NN;
    int* bucket_base = bucket_cnt + NBUCK;
    int* bucket_cursor = bucket_base + NBUCK + 1;

    // CSR build
    hipMemsetAsync(cnt_out, 0, (NN + NBUCK) * sizeof(int), stream);
    k_hist<<<256, 256, 0, stream>>>(dst, bucket_cnt);
    k_bscan<<<1, 1024, 0, stream>>>(bucket_cnt, bucket_base, bucket_cursor);
    k_pairs<<<(NE + 255) / 256, 256, 0, stream>>>(src, dst, bucket_cursor, cnt_out, E2);
    k_bcsr<<<NBUCK, 256, 0, stream>>>(E2, bucket_base, cnt_out, row_start, r_in, r_out, csr);

    // layer 0
    k_gemm0<<<(NN + 63) / 64, 256, 0, stream>>>(feats, W0, r_out, A);
    k_gather64<0><<<NN / 4, 256, 0, stream>>>(row_start, csr, A, r_in, r_out, b0, B, nullptr);

    // layer 1 (+ layer2 pre-GEMM)
    k_gather64<1><<<NN / 4, 256, 0, stream>>>(row_start, csr, B, r_in, r_out, b0, nullptr, G);
    k_mlp<<<(NN + 63) / 64, 256, 0, stream>>>(G, W1, b1, W2, r_out, C);

    // layer 2
    k_gather16<<<NN / 4, 256, 0, stream>>>(row_start, csr, C, r_in, b2, out);
}